// Round 1
// baseline (107.302 us; speedup 1.0000x reference)
//
#include <hip/hip_runtime.h>
#include <hip/hip_bf16.h>

// Sizes (fixed by the reference)
#define BI 64
#define BC 64
#define TCAP 64
#define D 1024
#define H 128
#define TIMG 36

// ---------------- K1: img_repr (mean over t) + normalized img_vec ----------------
__global__ __launch_bounds__(256) void k_img(const float* __restrict__ img,
                                             float* __restrict__ repr,
                                             float* __restrict__ ivec) {
    int i = blockIdx.x;
    int tid = threadIdx.x;
    const float* base = img + (size_t)i * TIMG * D;
    float s[4] = {0.f, 0.f, 0.f, 0.f};
    for (int t = 0; t < TIMG; ++t) {
#pragma unroll
        for (int r = 0; r < 4; ++r) s[r] += base[t * D + r * 256 + tid];
    }
    float local = 0.f;
#pragma unroll
    for (int r = 0; r < 4; ++r) {
        s[r] *= (1.f / 36.f);
        repr[i * D + r * 256 + tid] = s[r];
        local += s[r] * s[r];
    }
    // block reduction (4 waves of 64)
    for (int off = 32; off; off >>= 1) local += __shfl_xor(local, off);
    __shared__ float red[4];
    int wave = tid >> 6;
    if ((tid & 63) == 0) red[wave] = local;
    __syncthreads();
    float inv = rsqrtf(red[0] + red[1] + red[2] + red[3]);
#pragma unroll
    for (int r = 0; r < 4; ++r) ivec[i * D + r * 256 + tid] = s[r] * inv;
}

// ---------------- K2: per-channel partial sums over (b, t<36) ----------------
__global__ __launch_bounds__(256) void k_capstat(const float* __restrict__ cap,
                                                 float* __restrict__ part) {
    int d = blockIdx.x * 256 + threadIdx.x;
    int b = blockIdx.y;
    const float* base = cap + (size_t)b * TCAP * D;
    float s = 0.f, ss = 0.f;
#pragma unroll 4
    for (int t = 0; t < TIMG; ++t) {
        float x = base[t * D + d];
        s += x;
        ss += x * x;
    }
    part[b * 2048 + d] = s;
    part[b * 2048 + 1024 + d] = ss;
}

// ---------------- K3: finalize mu / inv_std ----------------
__global__ __launch_bounds__(256) void k_stat2(const float* __restrict__ part,
                                               float* __restrict__ mu,
                                               float* __restrict__ istd) {
    int d = blockIdx.x * 256 + threadIdx.x;
    float s = 0.f, ss = 0.f;
    for (int g = 0; g < BC; ++g) {
        s += part[g * 2048 + d];
        ss += part[g * 2048 + 1024 + d];
    }
    const float invN = 1.f / 2304.f;
    float m = s * invN;
    float v = ss * invN - m * m;
    mu[d] = m;
    istd[d] = rsqrtf(v + 1e-5f);
}

// ---------------- K4: CBN MLPs -> gam, bet (one block per image) ----------------
__global__ __launch_bounds__(256) void k_mlp(const float* __restrict__ repr,
                                             const float* __restrict__ Wg1, const float* __restrict__ bg1,
                                             const float* __restrict__ Wg2, const float* __restrict__ bg2,
                                             const float* __restrict__ Wb1, const float* __restrict__ bb1,
                                             const float* __restrict__ Wb2, const float* __restrict__ bb2,
                                             float* __restrict__ gam, float* __restrict__ bet) {
    __shared__ float r[D];
    __shared__ float h[256];  // h[0:128]=relu gamma hidden, h[128:256]=relu beta hidden
    int i = blockIdx.x, tid = threadIdx.x;
#pragma unroll
    for (int q = 0; q < 4; ++q) r[q * 256 + tid] = repr[i * D + q * 256 + tid];
    __syncthreads();
    {
        int hh = tid & 127;
        const float* W = (tid < 128) ? Wg1 : Wb1;
        const float* b1 = (tid < 128) ? bg1 : bb1;
        float acc = b1[hh];
        for (int d = 0; d < D; ++d) acc = fmaf(r[d], W[d * H + hh], acc);
        h[tid] = fmaxf(acc, 0.f);
    }
    __syncthreads();
#pragma unroll
    for (int q = 0; q < 4; ++q) {
        int d = q * 256 + tid;
        float g = bg2[d], bb = bb2[d];
        for (int hh = 0; hh < H; ++hh) {
            g = fmaf(h[hh], Wg2[hh * D + d], g);
            bb = fmaf(h[128 + hh], Wb2[hh * D + d], bb);
        }
        gam[i * D + d] = 1.f + g;
        bet[i * D + d] = bb;
    }
}

// ---------------- K5: main gated-softmax + dot kernel ----------------
// grid (b=64, igroup=8), 512 threads; each thread owns channels d0=tid, d1=tid+512
__global__ __launch_bounds__(512) void k_main(const float* __restrict__ cap,
                                              const float* __restrict__ mu,
                                              const float* __restrict__ istd,
                                              const float* __restrict__ gam,
                                              const float* __restrict__ bet,
                                              const float* __restrict__ ivec,
                                              float* __restrict__ out) {
    int b = blockIdx.x, ig = blockIdx.y, tid = threadIdx.x;
    int d0 = tid, d1 = tid + 512;
    const float* base = cap + (size_t)b * TCAP * D;
    float m0 = mu[d0], m1 = mu[d1];
    float is0 = istd[d0], is1 = istd[d1];
    float x0[TIMG], x1[TIMG];
#pragma unroll
    for (int t = 0; t < TIMG; ++t) {
        x0[t] = (base[t * D + d0] - m0) * is0;
        x1[t] = (base[t * D + d1] - m1) * is1;
    }
    __shared__ float red[16];
    const float A = 14.4269504089f;   // 10 * log2(e)
    const float INV = 0.0693147180560f; // ln(2) / 10
    for (int k = 0; k < 8; ++k) {
        int i = ig * 8 + k;
        float g0 = gam[i * D + d0], g1 = gam[i * D + d1];
        float be0 = bet[i * D + d0], be1 = bet[i * D + d1];
        float a0 = A * g0, a1 = A * g1;
        float c0 = A * (be0 - 6.f), c1 = A * (be1 - 6.f);
        float sw0 = 0.f, sx0 = 0.f, sw1 = 0.f, sx1 = 0.f;
#pragma unroll
        for (int t = 0; t < TIMG; ++t) {
            float arg0 = fmaf(a0, x0[t], c0);
            float e0 = __builtin_amdgcn_exp2f(arg0);
            float txt0 = fmaf(arg0, INV, 6.f);
            sw0 += e0;
            sx0 = fmaf(e0, txt0, sx0);
            float arg1 = fmaf(a1, x1[t], c1);
            float e1 = __builtin_amdgcn_exp2f(arg1);
            float txt1 = fmaf(arg1, INV, 6.f);
            sw1 += e1;
            sx1 = fmaf(e1, txt1, sx1);
        }
        float tv0 = sx0 / sw0, tv1 = sx1 / sw1;
        float iv0 = ivec[i * D + d0], iv1 = ivec[i * D + d1];
        float ss = tv0 * tv0 + tv1 * tv1;
        float sd = iv0 * tv0 + iv1 * tv1;
        for (int off = 32; off; off >>= 1) {
            ss += __shfl_xor(ss, off);
            sd += __shfl_xor(sd, off);
        }
        int wave = tid >> 6;
        if ((tid & 63) == 0) { red[wave] = ss; red[8 + wave] = sd; }
        __syncthreads();
        if (tid == 0) {
            float SS = 0.f, SD = 0.f;
#pragma unroll
            for (int w = 0; w < 8; ++w) { SS += red[w]; SD += red[8 + w]; }
            out[i * BC + b] = SD * rsqrtf(SS);
        }
        __syncthreads();
    }
}

extern "C" void kernel_launch(void* const* d_in, const int* in_sizes, int n_in,
                              void* d_out, int out_size, void* d_ws, size_t ws_size,
                              hipStream_t stream) {
    const float* img = (const float*)d_in[0];
    const float* cap = (const float*)d_in[1];
    // d_in[2] = lens (unused by the reference)
    const float* Wg1 = (const float*)d_in[3];
    const float* bg1 = (const float*)d_in[4];
    const float* Wg2 = (const float*)d_in[5];
    const float* bg2 = (const float*)d_in[6];
    const float* Wb1 = (const float*)d_in[7];
    const float* bb1 = (const float*)d_in[8];
    const float* Wb2 = (const float*)d_in[9];
    const float* bb2 = (const float*)d_in[10];

    float* ws = (float*)d_ws;
    float* repr = ws;              // 65536
    float* ivec = ws + 65536;      // 65536
    float* gam  = ws + 131072;     // 65536
    float* bet  = ws + 196608;     // 65536
    float* mu   = ws + 262144;     // 1024
    float* istd = ws + 263168;     // 1024
    float* part = ws + 264192;     // 64*2048 = 131072
    float* out = (float*)d_out;

    k_img<<<dim3(BI), dim3(256), 0, stream>>>(img, repr, ivec);
    k_capstat<<<dim3(4, BC), dim3(256), 0, stream>>>(cap, part);
    k_stat2<<<dim3(4), dim3(256), 0, stream>>>(part, mu, istd);
    k_mlp<<<dim3(BI), dim3(256), 0, stream>>>(repr, Wg1, bg1, Wg2, bg2,
                                              Wb1, bb1, Wb2, bb2, gam, bet);
    k_main<<<dim3(BC, 8), dim3(512), 0, stream>>>(cap, mu, istd, gam, bet, ivec, out);
}

// Round 3
// 75.341 us; speedup vs baseline: 1.4242x; 1.4242x over previous
//
#include <hip/hip_runtime.h>
#include <hip/hip_bf16.h>

// Sizes (fixed by the reference)
#define BI 64
#define BC 64
#define TCAP 64
#define D 1024
#define H 128
#define TIMG 36

// ---------------- K1: img_repr (mean over t) + normalized img_vec ----------------
__global__ __launch_bounds__(256) void k_img(const float* __restrict__ img,
                                             float* __restrict__ repr,
                                             float* __restrict__ ivec) {
    int i = blockIdx.x;
    int tid = threadIdx.x;
    const float* base = img + (size_t)i * TIMG * D;
    float s[4] = {0.f, 0.f, 0.f, 0.f};
    for (int t = 0; t < TIMG; ++t) {
#pragma unroll
        for (int r = 0; r < 4; ++r) s[r] += base[t * D + r * 256 + tid];
    }
    float local = 0.f;
#pragma unroll
    for (int r = 0; r < 4; ++r) {
        s[r] *= (1.f / 36.f);
        repr[i * D + r * 256 + tid] = s[r];
        local += s[r] * s[r];
    }
    for (int off = 32; off; off >>= 1) local += __shfl_xor(local, off);
    __shared__ float red[4];
    int wave = tid >> 6;
    if ((tid & 63) == 0) red[wave] = local;
    __syncthreads();
    float inv = rsqrtf(red[0] + red[1] + red[2] + red[3]);
#pragma unroll
    for (int r = 0; r < 4; ++r) ivec[i * D + r * 256 + tid] = s[r] * inv;
}

// ---------------- K2: per-channel partial sums over (b, t<36) ----------------
__global__ __launch_bounds__(256) void k_capstat(const float* __restrict__ cap,
                                                 float* __restrict__ part) {
    int d = blockIdx.x * 256 + threadIdx.x;
    int b = blockIdx.y;
    const float* base = cap + (size_t)b * TCAP * D;
    float s = 0.f, ss = 0.f;
#pragma unroll 4
    for (int t = 0; t < TIMG; ++t) {
        float x = base[t * D + d];
        s += x;
        ss += x * x;
    }
    part[b * 2048 + d] = s;
    part[b * 2048 + 1024 + d] = ss;
}

// ---------------- K3: finalize mu / inv_std ----------------
__global__ __launch_bounds__(256) void k_stat2(const float* __restrict__ part,
                                               float* __restrict__ mu,
                                               float* __restrict__ istd) {
    int d = blockIdx.x * 256 + threadIdx.x;
    float s = 0.f, ss = 0.f;
    for (int g = 0; g < BC; ++g) {
        s += part[g * 2048 + d];
        ss += part[g * 2048 + 1024 + d];
    }
    const float invN = 1.f / 2304.f;
    float m = s * invN;
    float v = ss * invN - m * m;
    mu[d] = m;
    istd[d] = rsqrtf(v + 1e-5f);
}

// ---------------- K4a: transpose+concat W1 -> W1T[256][1024] ----------------
// grid (16 dtiles, 2 ctiles, 2 matrices); block 256
__global__ __launch_bounds__(256) void k_w1t(const float* __restrict__ Wg1,
                                             const float* __restrict__ Wb1,
                                             float* __restrict__ W1T) {
    __shared__ float tile[64][65];
    const float* W = blockIdx.z ? Wb1 : Wg1;
    int d0 = blockIdx.x * 64, c0 = blockIdx.y * 64;
    int lane = threadIdx.x & 63, w = threadIdx.x >> 6;
#pragma unroll
    for (int k = 0; k < 16; ++k) {
        int dl = k * 4 + w;
        tile[dl][lane] = W[(size_t)(d0 + dl) * H + c0 + lane];
    }
    __syncthreads();
#pragma unroll
    for (int k = 0; k < 16; ++k) {
        int cl = k * 4 + w;
        W1T[(size_t)(blockIdx.z * 128 + c0 + cl) * D + d0 + lane] = tile[lane][cl];
    }
}

// ---------------- K4b: hidden layer, one wave per (i, c) output ----------------
// grid 4096 blocks x 256 threads (4 waves); o = blk*4+wave; i=o>>8, c=o&255
__global__ __launch_bounds__(256) void k_h(const float* __restrict__ repr,
                                           const float* __restrict__ W1T,
                                           const float* __restrict__ bg1,
                                           const float* __restrict__ bb1,
                                           float* __restrict__ hid) {
    int o = blockIdx.x * 4 + (threadIdx.x >> 6);
    int lane = threadIdx.x & 63;
    int i = o >> 8, c = o & 255;
    const float* r = repr + (size_t)i * D;
    const float* w = W1T + (size_t)c * D;
    float acc = 0.f;
#pragma unroll
    for (int k = 0; k < 16; ++k) acc = fmaf(r[k * 64 + lane], w[k * 64 + lane], acc);
    for (int off = 32; off; off >>= 1) acc += __shfl_xor(acc, off);
    if (lane == 0) {
        float b = (c < 128) ? bg1[c] : bb1[c - 128];
        hid[o] = fmaxf(acc + b, 0.f);
    }
}

// ---------------- K4c: second layer -> gam, bet; grid (64,4) x 256 ----------------
__global__ __launch_bounds__(256) void k_out(const float* __restrict__ hid,
                                             const float* __restrict__ Wg2, const float* __restrict__ bg2,
                                             const float* __restrict__ Wb2, const float* __restrict__ bb2,
                                             float* __restrict__ gam, float* __restrict__ bet) {
    int i = blockIdx.x;
    int d = blockIdx.y * 256 + threadIdx.x;
    __shared__ float h[256];
    h[threadIdx.x] = hid[i * 256 + threadIdx.x];
    __syncthreads();
    float g = bg2[d], bb = bb2[d];
#pragma unroll 4
    for (int hh = 0; hh < H; ++hh) {
        g = fmaf(h[hh], Wg2[(size_t)hh * D + d], g);
        bb = fmaf(h[128 + hh], Wb2[(size_t)hh * D + d], bb);
    }
    gam[(size_t)i * D + d] = 1.f + g;
    bet[(size_t)i * D + d] = bb;
}

// ---------------- K5: main gated-softmax + dot kernel ----------------
__global__ __launch_bounds__(512) void k_main(const float* __restrict__ cap,
                                              const float* __restrict__ mu,
                                              const float* __restrict__ istd,
                                              const float* __restrict__ gam,
                                              const float* __restrict__ bet,
                                              const float* __restrict__ ivec,
                                              float* __restrict__ out) {
    int b = blockIdx.x, ig = blockIdx.y, tid = threadIdx.x;
    int d0 = tid, d1 = tid + 512;
    const float* base = cap + (size_t)b * TCAP * D;
    float m0 = mu[d0], m1 = mu[d1];
    float is0 = istd[d0], is1 = istd[d1];
    float x0[TIMG], x1[TIMG];
#pragma unroll
    for (int t = 0; t < TIMG; ++t) {
        x0[t] = (base[t * D + d0] - m0) * is0;
        x1[t] = (base[t * D + d1] - m1) * is1;
    }
    __shared__ float red[16];
    const float A = 14.4269504089f;     // 10 * log2(e)
    const float INV = 0.0693147180560f; // ln(2) / 10
    for (int k = 0; k < 8; ++k) {
        int i = ig * 8 + k;
        float g0 = gam[i * D + d0], g1 = gam[i * D + d1];
        float be0 = bet[i * D + d0], be1 = bet[i * D + d1];
        float a0 = A * g0, a1 = A * g1;
        float c0 = A * (be0 - 6.f), c1 = A * (be1 - 6.f);
        float sw0 = 0.f, sx0 = 0.f, sw1 = 0.f, sx1 = 0.f;
#pragma unroll
        for (int t = 0; t < TIMG; ++t) {
            float arg0 = fmaf(a0, x0[t], c0);
            float e0 = __builtin_amdgcn_exp2f(arg0);
            float txt0 = fmaf(arg0, INV, 6.f);
            sw0 += e0;
            sx0 = fmaf(e0, txt0, sx0);
            float arg1 = fmaf(a1, x1[t], c1);
            float e1 = __builtin_amdgcn_exp2f(arg1);
            float txt1 = fmaf(arg1, INV, 6.f);
            sw1 += e1;
            sx1 = fmaf(e1, txt1, sx1);
        }
        float tv0 = sx0 / sw0, tv1 = sx1 / sw1;
        float iv0 = ivec[i * D + d0], iv1 = ivec[i * D + d1];
        float ss = tv0 * tv0 + tv1 * tv1;
        float sd = iv0 * tv0 + iv1 * tv1;
        for (int off = 32; off; off >>= 1) {
            ss += __shfl_xor(ss, off);
            sd += __shfl_xor(sd, off);
        }
        int wave = tid >> 6;
        if ((tid & 63) == 0) { red[wave] = ss; red[8 + wave] = sd; }
        __syncthreads();
        if (tid == 0) {
            float SS = 0.f, SD = 0.f;
#pragma unroll
            for (int w = 0; w < 8; ++w) { SS += red[w]; SD += red[8 + w]; }
            out[i * BC + b] = SD * rsqrtf(SS);
        }
        __syncthreads();
    }
}

extern "C" void kernel_launch(void* const* d_in, const int* in_sizes, int n_in,
                              void* d_out, int out_size, void* d_ws, size_t ws_size,
                              hipStream_t stream) {
    const float* img = (const float*)d_in[0];
    const float* cap = (const float*)d_in[1];
    // d_in[2] = lens (unused by the reference)
    const float* Wg1 = (const float*)d_in[3];
    const float* bg1 = (const float*)d_in[4];
    const float* Wg2 = (const float*)d_in[5];
    const float* bg2 = (const float*)d_in[6];
    const float* Wb1 = (const float*)d_in[7];
    const float* bb1 = (const float*)d_in[8];
    const float* Wb2 = (const float*)d_in[9];
    const float* bb2 = (const float*)d_in[10];

    float* ws = (float*)d_ws;
    float* repr = ws;                // 65536
    float* ivec = ws + 65536;        // 65536
    float* gam  = ws + 131072;       // 65536
    float* bet  = ws + 196608;       // 65536
    float* mu   = ws + 262144;       // 1024
    float* istd = ws + 263168;       // 1024
    float* part = ws + 264192;       // 131072
    float* W1T  = ws + 395264;       // 262144
    float* hid  = ws + 657408;       // 16384
    float* out = (float*)d_out;

    k_img<<<dim3(BI), dim3(256), 0, stream>>>(img, repr, ivec);
    k_capstat<<<dim3(4, BC), dim3(256), 0, stream>>>(cap, part);
    k_stat2<<<dim3(4), dim3(256), 0, stream>>>(part, mu, istd);
    k_w1t<<<dim3(16, 2, 2), dim3(256), 0, stream>>>(Wg1, Wb1, W1T);
    k_h<<<dim3(4096), dim3(256), 0, stream>>>(repr, W1T, bg1, bb1, hid);
    k_out<<<dim3(BI, 4), dim3(256), 0, stream>>>(hid, Wg2, bg2, Wb2, bb2, gam, bet);
    k_main<<<dim3(BC, 8), dim3(512), 0, stream>>>(cap, mu, istd, gam, bet, ivec, out);
}

// Round 4
// 58.708 us; speedup vs baseline: 1.8277x; 1.2833x over previous
//
#include <hip/hip_runtime.h>
#include <hip/hip_bf16.h>

// Sizes (fixed by the reference)
#define BI 64
#define BC 64
#define TCAP 64
#define D 1024
#define H 128
#define TIMG 36

// ---------------- Kernel A: img stats | cap partial stats | W1 transpose ----------------
// grid 384 x 256:  blk<64: img   64<=blk<320: capstat   320<=blk: w1t
__global__ __launch_bounds__(256) void k_pre(const float* __restrict__ img,
                                             const float* __restrict__ cap,
                                             const float* __restrict__ Wg1,
                                             const float* __restrict__ Wb1,
                                             float* __restrict__ repr,
                                             float* __restrict__ ivec,
                                             float* __restrict__ part,
                                             float* __restrict__ W1T) {
    int blk = blockIdx.x, tid = threadIdx.x;
    if (blk < 64) {
        // ---- img_repr mean + l2-normalized img_vec ----
        int i = blk;
        const float* base = img + (size_t)i * TIMG * D;
        float s[4] = {0.f, 0.f, 0.f, 0.f};
        for (int t = 0; t < TIMG; ++t) {
#pragma unroll
            for (int r = 0; r < 4; ++r) s[r] += base[t * D + r * 256 + tid];
        }
        float local = 0.f;
#pragma unroll
        for (int r = 0; r < 4; ++r) {
            s[r] *= (1.f / 36.f);
            repr[i * D + r * 256 + tid] = s[r];
            local += s[r] * s[r];
        }
        for (int off = 32; off; off >>= 1) local += __shfl_xor(local, off);
        __shared__ float red[4];
        int wave = tid >> 6;
        if ((tid & 63) == 0) red[wave] = local;
        __syncthreads();
        float inv = rsqrtf(red[0] + red[1] + red[2] + red[3]);
#pragma unroll
        for (int r = 0; r < 4; ++r) ivec[i * D + r * 256 + tid] = s[r] * inv;
    } else if (blk < 320) {
        // ---- per-channel partial sums over t<36 for one caption b ----
        int idx = blk - 64;
        int b = idx >> 2;
        int d = (idx & 3) * 256 + tid;
        const float* base = cap + (size_t)b * TCAP * D;
        float s = 0.f, ss = 0.f;
#pragma unroll 4
        for (int t = 0; t < TIMG; ++t) {
            float x = base[t * D + d];
            s += x;
            ss += x * x;
        }
        part[b * 2048 + d] = s;
        part[b * 2048 + 1024 + d] = ss;
    } else {
        // ---- transpose+concat W1 -> W1T[256][1024] ----
        __shared__ float tile[64][65];
        int idx = blk - 320;
        int bx = idx & 15, by = (idx >> 4) & 1, bz = idx >> 5;
        const float* W = bz ? Wb1 : Wg1;
        int d0 = bx * 64, c0 = by * 64;
        int lane = tid & 63, w = tid >> 6;
#pragma unroll
        for (int k = 0; k < 16; ++k) {
            int dl = k * 4 + w;
            tile[dl][lane] = W[(size_t)(d0 + dl) * H + c0 + lane];
        }
        __syncthreads();
#pragma unroll
        for (int k = 0; k < 16; ++k) {
            int cl = k * 4 + w;
            W1T[(size_t)(bz * 128 + c0 + cl) * D + d0 + lane] = tile[lane][cl];
        }
    }
}

// ---------------- Kernel B: stat finalize | hidden layer ----------------
// grid 4100 x 256: blk<4: mu/istd   else: one wave per (i,c) hidden output
__global__ __launch_bounds__(256) void k_mid(const float* __restrict__ part,
                                             const float* __restrict__ repr,
                                             const float* __restrict__ W1T,
                                             const float* __restrict__ bg1,
                                             const float* __restrict__ bb1,
                                             float* __restrict__ mu,
                                             float* __restrict__ istd,
                                             float* __restrict__ hid) {
    int blk = blockIdx.x, tid = threadIdx.x;
    if (blk < 4) {
        int d = blk * 256 + tid;
        float s = 0.f, ss = 0.f;
        for (int g = 0; g < BC; ++g) {
            s += part[g * 2048 + d];
            ss += part[g * 2048 + 1024 + d];
        }
        const float invN = 1.f / 2304.f;
        float m = s * invN;
        float v = ss * invN - m * m;
        mu[d] = m;
        istd[d] = rsqrtf(v + 1e-5f);
    } else {
        int o = (blk - 4) * 4 + (tid >> 6);
        int lane = tid & 63;
        int i = o >> 8, c = o & 255;
        const float* r = repr + (size_t)i * D;
        const float* w = W1T + (size_t)c * D;
        float acc = 0.f;
#pragma unroll
        for (int k = 0; k < 16; ++k) acc = fmaf(r[k * 64 + lane], w[k * 64 + lane], acc);
        for (int off = 32; off; off >>= 1) acc += __shfl_xor(acc, off);
        if (lane == 0) {
            float b = (c < 128) ? bg1[c] : bb1[c - 128];
            hid[o] = fmaxf(acc + b, 0.f);
        }
    }
}

// ---------------- Kernel C: second MLP layer -> gam, bet ----------------
// grid 256 x 256: i = blk>>2, d = (blk&3)*256 + tid
__global__ __launch_bounds__(256) void k_out(const float* __restrict__ hid,
                                             const float* __restrict__ Wg2, const float* __restrict__ bg2,
                                             const float* __restrict__ Wb2, const float* __restrict__ bb2,
                                             float* __restrict__ gam, float* __restrict__ bet) {
    int i = blockIdx.x >> 2;
    int d = (blockIdx.x & 3) * 256 + threadIdx.x;
    __shared__ float h[256];
    h[threadIdx.x] = hid[i * 256 + threadIdx.x];
    __syncthreads();
    float g = bg2[d], bb = bb2[d];
#pragma unroll 4
    for (int hh = 0; hh < H; ++hh) {
        g = fmaf(h[hh], Wg2[(size_t)hh * D + d], g);
        bb = fmaf(h[128 + hh], Wb2[(size_t)hh * D + d], bb);
    }
    gam[(size_t)i * D + d] = 1.f + g;
    bet[(size_t)i * D + d] = bb;
}

// ---------------- Kernel D: main gated-softmax + dot ----------------
// grid (b=64, ig=8) x 512; each thread owns channels d0=tid, d1=tid+512
__global__ __launch_bounds__(512) void k_main(const float* __restrict__ cap,
                                              const float* __restrict__ mu,
                                              const float* __restrict__ istd,
                                              const float* __restrict__ gam,
                                              const float* __restrict__ bet,
                                              const float* __restrict__ ivec,
                                              float* __restrict__ out) {
    int b = blockIdx.x, ig = blockIdx.y, tid = threadIdx.x;
    int d0 = tid, d1 = tid + 512;
    const float* base = cap + (size_t)b * TCAP * D;
    float m0 = mu[d0], m1 = mu[d1];
    float is0 = istd[d0], is1 = istd[d1];
    float x0[TIMG], x1[TIMG];
#pragma unroll
    for (int t = 0; t < TIMG; ++t) {
        x0[t] = (base[t * D + d0] - m0) * is0;
        x1[t] = (base[t * D + d1] - m1) * is1;
    }
    __shared__ float redS[8][8], redD[8][8];
    const float A = 14.4269504089f;     // 10 * log2(e)
    const float INV = 0.0693147180560f; // ln(2) / 10
    int wave = tid >> 6;
#pragma unroll
    for (int k = 0; k < 8; ++k) {
        int i = ig * 8 + k;
        float g0 = gam[i * D + d0], g1 = gam[i * D + d1];
        float be0 = bet[i * D + d0], be1 = bet[i * D + d1];
        float a0 = A * g0, a1 = A * g1;
        float c0 = A * (be0 - 6.f), c1 = A * (be1 - 6.f);
        float sw0 = 0.f, sxa0 = 0.f, sw1 = 0.f, sxa1 = 0.f;
#pragma unroll
        for (int t = 0; t < TIMG; ++t) {
            float arg0 = fmaf(a0, x0[t], c0);
            float e0 = __builtin_amdgcn_exp2f(arg0);
            sw0 += e0;
            sxa0 = fmaf(e0, arg0, sxa0);
            float arg1 = fmaf(a1, x1[t], c1);
            float e1 = __builtin_amdgcn_exp2f(arg1);
            sw1 += e1;
            sxa1 = fmaf(e1, arg1, sxa1);
        }
        // tv = INV * (sxa/sw) + 6   (since txt = arg*INV + 6)
        float tv0 = fmaf(INV, sxa0 / sw0, 6.f);
        float tv1 = fmaf(INV, sxa1 / sw1, 6.f);
        float iv0 = ivec[i * D + d0], iv1 = ivec[i * D + d1];
        float ss = tv0 * tv0 + tv1 * tv1;
        float sd = iv0 * tv0 + iv1 * tv1;
        for (int off = 32; off; off >>= 1) {
            ss += __shfl_xor(ss, off);
            sd += __shfl_xor(sd, off);
        }
        if ((tid & 63) == 0) { redS[k][wave] = ss; redD[k][wave] = sd; }
    }
    __syncthreads();
    if (tid < 64) {
        int k = tid >> 3, w = tid & 7;
        float s = redS[k][w], d = redD[k][w];
#pragma unroll
        for (int off = 1; off < 8; off <<= 1) {
            s += __shfl_xor(s, off);
            d += __shfl_xor(d, off);
        }
        if (w == 0) {
            int i = ig * 8 + k;
            out[i * BC + b] = d * rsqrtf(s);
        }
    }
}

extern "C" void kernel_launch(void* const* d_in, const int* in_sizes, int n_in,
                              void* d_out, int out_size, void* d_ws, size_t ws_size,
                              hipStream_t stream) {
    const float* img = (const float*)d_in[0];
    const float* cap = (const float*)d_in[1];
    // d_in[2] = lens (unused by the reference)
    const float* Wg1 = (const float*)d_in[3];
    const float* bg1 = (const float*)d_in[4];
    const float* Wg2 = (const float*)d_in[5];
    const float* bg2 = (const float*)d_in[6];
    const float* Wb1 = (const float*)d_in[7];
    const float* bb1 = (const float*)d_in[8];
    const float* Wb2 = (const float*)d_in[9];
    const float* bb2 = (const float*)d_in[10];

    float* ws = (float*)d_ws;
    float* repr = ws;                // 65536
    float* ivec = ws + 65536;        // 65536
    float* gam  = ws + 131072;       // 65536
    float* bet  = ws + 196608;       // 65536
    float* mu   = ws + 262144;       // 1024
    float* istd = ws + 263168;       // 1024
    float* part = ws + 264192;       // 131072
    float* W1T  = ws + 395264;       // 262144
    float* hid  = ws + 657408;       // 16384
    float* out = (float*)d_out;

    k_pre<<<dim3(384), dim3(256), 0, stream>>>(img, cap, Wg1, Wb1, repr, ivec, part, W1T);
    k_mid<<<dim3(4100), dim3(256), 0, stream>>>(part, repr, W1T, bg1, bb1, mu, istd, hid);
    k_out<<<dim3(256), dim3(256), 0, stream>>>(hid, Wg2, bg2, Wb2, bb2, gam, bet);
    k_main<<<dim3(BC, 8), dim3(512), 0, stream>>>(cap, mu, istd, gam, bet, ivec, out);
}

// Round 5
// 55.440 us; speedup vs baseline: 1.9355x; 1.0589x over previous
//
#include <hip/hip_runtime.h>
#include <hip/hip_bf16.h>

// Sizes (fixed by the reference)
#define BI 64
#define BC 64
#define TCAP 64
#define D 1024
#define H 128
#define TIMG 36

// ---------------- Kernel A: img stats | cap partial stats | W1 transpose ----------------
// grid 192 x 256:  blk<64: img   64<=blk<128: capstat   128<=blk: w1t
__global__ __launch_bounds__(256) void k_pre(const float* __restrict__ img,
                                             const float* __restrict__ cap,
                                             const float* __restrict__ Wg1,
                                             const float* __restrict__ Wb1,
                                             float* __restrict__ repr,
                                             float* __restrict__ ivec,
                                             float* __restrict__ part,
                                             float* __restrict__ W1T) {
    int blk = blockIdx.x, tid = threadIdx.x;
    if (blk < 64) {
        // ---- img_repr mean + l2-normalized img_vec (thread owns 4 channels) ----
        int i = blk;
        const float4* base = (const float4*)(img + (size_t)i * TIMG * D);
        float4 s = {0.f, 0.f, 0.f, 0.f};
        for (int t = 0; t < TIMG; ++t) {
            float4 v = base[t * 256 + tid];
            s.x += v.x; s.y += v.y; s.z += v.z; s.w += v.w;
        }
        s.x *= (1.f / 36.f); s.y *= (1.f / 36.f); s.z *= (1.f / 36.f); s.w *= (1.f / 36.f);
        ((float4*)(repr + (size_t)i * D))[tid] = s;
        float local = s.x * s.x + s.y * s.y + s.z * s.z + s.w * s.w;
        for (int off = 32; off; off >>= 1) local += __shfl_xor(local, off);
        __shared__ float red[4];
        int wave = tid >> 6;
        if ((tid & 63) == 0) red[wave] = local;
        __syncthreads();
        float inv = rsqrtf(red[0] + red[1] + red[2] + red[3]);
        float4 o = {s.x * inv, s.y * inv, s.z * inv, s.w * inv};
        ((float4*)(ivec + (size_t)i * D))[tid] = o;
    } else if (blk < 128) {
        // ---- per-channel partial sums over t<36 for one caption b (4 ch/thread) ----
        int b = blk - 64;
        const float4* base = (const float4*)(cap + (size_t)b * TCAP * D);
        float4 s = {0.f, 0.f, 0.f, 0.f}, ss = {0.f, 0.f, 0.f, 0.f};
        for (int t = 0; t < TIMG; ++t) {
            float4 v = base[t * 256 + tid];
            s.x += v.x; s.y += v.y; s.z += v.z; s.w += v.w;
            ss.x = fmaf(v.x, v.x, ss.x); ss.y = fmaf(v.y, v.y, ss.y);
            ss.z = fmaf(v.z, v.z, ss.z); ss.w = fmaf(v.w, v.w, ss.w);
        }
        ((float4*)(part + b * 2048))[tid] = s;
        ((float4*)(part + b * 2048 + 1024))[tid] = ss;
    } else {
        // ---- transpose+concat W1 -> W1T[256][1024] ----
        __shared__ float tile[64][65];
        int idx = blk - 128;
        int bx = idx & 15, by = (idx >> 4) & 1, bz = idx >> 5;
        const float* W = bz ? Wb1 : Wg1;
        int d0 = bx * 64, c0 = by * 64;
        int lane = tid & 63, w = tid >> 6;
#pragma unroll
        for (int k = 0; k < 16; ++k) {
            int dl = k * 4 + w;
            tile[dl][lane] = W[(size_t)(d0 + dl) * H + c0 + lane];
        }
        __syncthreads();
#pragma unroll
        for (int k = 0; k < 16; ++k) {
            int cl = k * 4 + w;
            W1T[(size_t)(bz * 128 + c0 + cl) * D + d0 + lane] = tile[lane][cl];
        }
    }
}

// ---------------- Kernel B: stat finalize | hidden layer ----------------
// grid 4100 x 256: blk<4: mu/istd   else: one wave per (i,c) hidden output
__global__ __launch_bounds__(256) void k_mid(const float* __restrict__ part,
                                             const float* __restrict__ repr,
                                             const float* __restrict__ W1T,
                                             const float* __restrict__ bg1,
                                             const float* __restrict__ bb1,
                                             float* __restrict__ mu,
                                             float* __restrict__ istd,
                                             float* __restrict__ hid) {
    int blk = blockIdx.x, tid = threadIdx.x;
    if (blk < 4) {
        int d = blk * 256 + tid;
        float s = 0.f, ss = 0.f;
        for (int g = 0; g < BC; ++g) {
            s += part[g * 2048 + d];
            ss += part[g * 2048 + 1024 + d];
        }
        const float invN = 1.f / 2304.f;
        float m = s * invN;
        float v = ss * invN - m * m;
        mu[d] = m;
        istd[d] = rsqrtf(v + 1e-5f);
    } else {
        int o = (blk - 4) * 4 + (tid >> 6);
        int lane = tid & 63;
        int i = o >> 8, c = o & 255;
        const float4* r = (const float4*)(repr + (size_t)i * D);
        const float4* w = (const float4*)(W1T + (size_t)c * D);
        float acc = 0.f;
#pragma unroll
        for (int k = 0; k < 4; ++k) {
            float4 rv = r[k * 64 + lane];
            float4 wv = w[k * 64 + lane];
            acc = fmaf(rv.x, wv.x, acc);
            acc = fmaf(rv.y, wv.y, acc);
            acc = fmaf(rv.z, wv.z, acc);
            acc = fmaf(rv.w, wv.w, acc);
        }
        for (int off = 32; off; off >>= 1) acc += __shfl_xor(acc, off);
        if (lane == 0) {
            float b = (c < 128) ? bg1[c] : bb1[c - 128];
            hid[o] = fmaxf(acc + b, 0.f);
        }
    }
}

// ---------------- Kernel C: second MLP layer -> gam, bet (float2 per thread) ----------------
// grid 128 x 256: i = blk>>1, d2 = (blk&1)*256 + tid  (float2 channel index)
__global__ __launch_bounds__(256) void k_out(const float* __restrict__ hid,
                                             const float* __restrict__ Wg2, const float* __restrict__ bg2,
                                             const float* __restrict__ Wb2, const float* __restrict__ bb2,
                                             float* __restrict__ gam, float* __restrict__ bet) {
    int i = blockIdx.x >> 1;
    int d2 = (blockIdx.x & 1) * 256 + threadIdx.x;
    __shared__ float h[256];
    h[threadIdx.x] = hid[i * 256 + threadIdx.x];
    __syncthreads();
    float2 g = ((const float2*)bg2)[d2];
    float2 bb = ((const float2*)bb2)[d2];
#pragma unroll 4
    for (int hh = 0; hh < H; ++hh) {
        float2 wg = ((const float2*)(Wg2 + (size_t)hh * D))[d2];
        float2 wb = ((const float2*)(Wb2 + (size_t)hh * D))[d2];
        float hg = h[hh], hb = h[128 + hh];
        g.x = fmaf(hg, wg.x, g.x);
        g.y = fmaf(hg, wg.y, g.y);
        bb.x = fmaf(hb, wb.x, bb.x);
        bb.y = fmaf(hb, wb.y, bb.y);
    }
    float2 go = {1.f + g.x, 1.f + g.y};
    ((float2*)(gam + (size_t)i * D))[d2] = go;
    ((float2*)(bet + (size_t)i * D))[d2] = bb;
}

// ---------------- Kernel D: main gated-softmax + dot ----------------
// grid (b=64, ig=8) x 512; thread owns adjacent channel pair (2tid, 2tid+1)
__global__ __launch_bounds__(512) void k_main(const float* __restrict__ cap,
                                              const float* __restrict__ mu,
                                              const float* __restrict__ istd,
                                              const float* __restrict__ gam,
                                              const float* __restrict__ bet,
                                              const float* __restrict__ ivec,
                                              float* __restrict__ out) {
    int b = blockIdx.x, ig = blockIdx.y, tid = threadIdx.x;
    const float2* base = (const float2*)(cap + (size_t)b * TCAP * D);
    float2 mu2 = ((const float2*)mu)[tid];
    float2 is2 = ((const float2*)istd)[tid];
    const float A = 14.4269504089f;     // 10 * log2(e)
    const float INV = 0.0693147180560f; // ln(2) / 10

    float a0[8], a1[8], c0[8], c1[8];
    float sw0[8], sw1[8], sxa0[8], sxa1[8];
#pragma unroll
    for (int k = 0; k < 8; ++k) {
        int i = ig * 8 + k;
        float2 g = ((const float2*)(gam + (size_t)i * D))[tid];
        float2 be = ((const float2*)(bet + (size_t)i * D))[tid];
        a0[k] = A * g.x;
        a1[k] = A * g.y;
        c0[k] = A * (be.x - 6.f);
        c1[k] = A * (be.y - 6.f);
        sw0[k] = 0.f; sw1[k] = 0.f; sxa0[k] = 0.f; sxa1[k] = 0.f;
    }
#pragma unroll 4
    for (int t = 0; t < TIMG; ++t) {
        float2 cp = base[t * 512 + tid];
        float x0 = (cp.x - mu2.x) * is2.x;
        float x1 = (cp.y - mu2.y) * is2.y;
#pragma unroll
        for (int k = 0; k < 8; ++k) {
            float arg0 = fmaf(a0[k], x0, c0[k]);
            float e0 = __builtin_amdgcn_exp2f(arg0);
            sw0[k] += e0;
            sxa0[k] = fmaf(e0, arg0, sxa0[k]);
            float arg1 = fmaf(a1[k], x1, c1[k]);
            float e1 = __builtin_amdgcn_exp2f(arg1);
            sw1[k] += e1;
            sxa1[k] = fmaf(e1, arg1, sxa1[k]);
        }
    }
    __shared__ float redS[8][8], redD[8][8];
    int wave = tid >> 6;
#pragma unroll
    for (int k = 0; k < 8; ++k) {
        int i = ig * 8 + k;
        float2 iv = ((const float2*)(ivec + (size_t)i * D))[tid];
        // tv = INV * (sxa/sw) + 6   (since txt = arg*INV + 6)
        float tv0 = fmaf(INV, sxa0[k] / sw0[k], 6.f);
        float tv1 = fmaf(INV, sxa1[k] / sw1[k], 6.f);
        float ss = tv0 * tv0 + tv1 * tv1;
        float sd = iv.x * tv0 + iv.y * tv1;
        for (int off = 32; off; off >>= 1) {
            ss += __shfl_xor(ss, off);
            sd += __shfl_xor(sd, off);
        }
        if ((tid & 63) == 0) { redS[k][wave] = ss; redD[k][wave] = sd; }
    }
    __syncthreads();
    if (tid < 64) {
        int k = tid >> 3, w = tid & 7;
        float s = redS[k][w], d = redD[k][w];
#pragma unroll
        for (int off = 1; off < 8; off <<= 1) {
            s += __shfl_xor(s, off);
            d += __shfl_xor(d, off);
        }
        if (w == 0) {
            int i = ig * 8 + k;
            out[i * BC + b] = d * rsqrtf(s);
        }
    }
}

extern "C" void kernel_launch(void* const* d_in, const int* in_sizes, int n_in,
                              void* d_out, int out_size, void* d_ws, size_t ws_size,
                              hipStream_t stream) {
    const float* img = (const float*)d_in[0];
    const float* cap = (const float*)d_in[1];
    // d_in[2] = lens (unused by the reference)
    const float* Wg1 = (const float*)d_in[3];
    const float* bg1 = (const float*)d_in[4];
    const float* Wg2 = (const float*)d_in[5];
    const float* bg2 = (const float*)d_in[6];
    const float* Wb1 = (const float*)d_in[7];
    const float* bb1 = (const float*)d_in[8];
    const float* Wb2 = (const float*)d_in[9];
    const float* bb2 = (const float*)d_in[10];

    float* ws = (float*)d_ws;
    float* repr = ws;                // 65536
    float* ivec = ws + 65536;        // 65536
    float* gam  = ws + 131072;       // 65536
    float* bet  = ws + 196608;       // 65536
    float* mu   = ws + 262144;       // 1024
    float* istd = ws + 263168;       // 1024
    float* part = ws + 264192;       // 131072
    float* W1T  = ws + 395264;       // 262144
    float* hid  = ws + 657408;       // 16384
    float* out = (float*)d_out;

    k_pre<<<dim3(192), dim3(256), 0, stream>>>(img, cap, Wg1, Wb1, repr, ivec, part, W1T);
    k_mid<<<dim3(4100), dim3(256), 0, stream>>>(part, repr, W1T, bg1, bb1, mu, istd, hid);
    k_out<<<dim3(128), dim3(256), 0, stream>>>(hid, Wg2, bg2, Wb2, bb2, gam, bet);
    k_main<<<dim3(BC, 8), dim3(512), 0, stream>>>(cap, mu, istd, gam, bet, ivec, out);
}